// Round 13
// baseline (111.400 us; speedup 1.0000x reference)
//
#include <hip/hip_runtime.h>
#include <stdint.h>

// Shapes (fixed for this problem)
#define B_   4
#define H_   16
#define S_   1024
#define D_   128
#define BN   32                  // K/V rows per iteration
#define NKT  (S_ / BN)           // 32
#define NTHREADS 256             // 4 waves x 32 q-rows = 128 q/block (32x32 MFMA)

typedef float f32x4  __attribute__((ext_vector_type(4)));
typedef float f32x16 __attribute__((ext_vector_type(16)));
typedef short s16x8  __attribute__((ext_vector_type(8)));   // 8 bf16 (MFMA A/B frag)
typedef short s16x4  __attribute__((ext_vector_type(4)));

static __device__ __forceinline__ uint16_t f2bf(float f) {
  uint32_t u = __float_as_uint(f);
  u += 0x7FFFu + ((u >> 16) & 1u);          // round-to-nearest-even
  return (uint16_t)(u >> 16);
}
static __device__ __forceinline__ float bf2f(uint16_t h) {
  return __uint_as_float((uint32_t)h << 16);
}

static __device__ __forceinline__ void gl16(const void* g, void* l) {
  __builtin_amdgcn_global_load_lds(
      (const __attribute__((address_space(1))) unsigned int*)g,
      (__attribute__((address_space(3))) unsigned int*)l, 16, 0, 0);
}

// ws layout for 32x32x16 fragments:
//  K tile (bh,kt) 8192B: chunk16B[ks*64 + lane] = K[kt*32 + (lane&31)][16ks + 8*(lane>>5) ..+7]
//    (A-operand of swapped QK: row=kv=lane&31, k=d)
//  V tile (bh,kt) 8192B: chunk16B[(dc*2+s)*64 + lane] =
//    V[kt*32 + 16s + 8*(lane>>5) ..+7][32dc + (lane&31)]   (B-operand of PV)
//  mask (row-contiguous): wsM[(b*1024 + r)*32 + w] = bits of mask[b][r][32w..+31]
#define WSK_BYTES  16777216
#define WSV_BYTES  16777216
#define WSM_BYTES  524288
#define WS_NEED    (WSK_BYTES + WSV_BYTES + WSM_BYTES)

// ============================ pre-pass ====================================
__global__ __launch_bounds__(256)
void prepass_kernel(const float* __restrict__ k, const float* __restrict__ v,
                    const int* __restrict__ mask,
                    char* __restrict__ wsK, char* __restrict__ wsV,
                    uint32_t* __restrict__ wsM)
{
  int gid = blockIdx.x * 256 + threadIdx.x;
  if (gid < 1048576) {                       // ---- K chunks (A-frag order) ----
    int tile = gid >> 9, c = gid & 511;
    int ks = c >> 6, l = c & 63;             // ks 0..7
    int kv = l & 31, tt = l >> 5;
    const float* src = k + ((size_t)(tile >> 5) * S_ + (tile & 31) * 32 + kv) * D_
                         + 16 * ks + 8 * tt;
    f32x4 x0 = *(const f32x4*)src;
    f32x4 x1 = *(const f32x4*)(src + 4);
    s16x8 h;
    h[0]=f2bf(x0[0]); h[1]=f2bf(x0[1]); h[2]=f2bf(x0[2]); h[3]=f2bf(x0[3]);
    h[4]=f2bf(x1[0]); h[5]=f2bf(x1[1]); h[6]=f2bf(x1[2]); h[7]=f2bf(x1[3]);
    *(s16x8*)(wsK + (size_t)gid * 16) = h;
  } else if (gid < 2097152) {                // ---- V chunks (B-frag order) ----
    int gv = gid - 1048576;
    int tile = gv >> 9, c = gv & 511;
    int l = c & 63;
    int d   = 32 * (c >> 7) + (l & 31);
    int kv0 = 16 * ((c >> 6) & 1) + 8 * (l >> 5);
    const float* src = v + ((size_t)(tile >> 5) * S_ + (tile & 31) * 32 + kv0) * D_ + d;
    s16x8 h;
    #pragma unroll
    for (int e = 0; e < 8; ++e) h[e] = f2bf(src[(size_t)e * D_]);
    *(s16x8*)(wsV + (size_t)gv * 16) = h;
  } else if (gid < 2228224) {                // ---- mask bitwords (row-contiguous) ----
    int gm = gid - 2097152;                  // 0..131071
    const int* src = mask + (size_t)(gm >> 5) * S_ + (gm & 31) * 32;
    uint32_t bits = 0;
    #pragma unroll
    for (int i = 0; i < 32; ++i) bits |= (src[i] != 0 ? 1u : 0u) << i;
    wsM[gm] = bits;
  }
}

// ============================ main kernel =================================
// LDS (41984 B): lK dbuf 16K | lV dbuf 16K | lS 4 x 2304 (32 rows x 72B, wave-
// private). All MFMA-operand reads are base + lane*16 (conflict-free). Grid
// 512 = 2 blocks/CU (8 waves) — acceptable because the kernel is store-BW
// bound after the 32x32 LDS-halving (LDS ~23us total vs HBM-write ~45us).
__global__ __launch_bounds__(NTHREADS)
__attribute__((amdgpu_waves_per_eu(2)))      // 256-VGPR budget; ~145 live regs
void attn_relu15_main(const float* __restrict__ q,
                      const char* __restrict__ wsK, const char* __restrict__ wsV,
                      const uint32_t* __restrict__ wsM,
                      float* __restrict__ outp, float* __restrict__ attnp)
{
  const int blk = blockIdx.x;                  // 512 blocks
  const int g   = (blk & 7) * 64 + (blk >> 3); // XCD-grouped bijection
  const int bh  = g >> 3;                      // 8 heads per XCD
  const int qt  = g & 7;                       // 128-row q tile
  const int b   = bh >> 4;

  const int tid  = threadIdx.x;
  const int lane = tid & 63;
  const int wv   = tid >> 6;
  const int q31  = lane & 31;
  const int t    = lane >> 5;                  // half-wave index
  const int qrow0 = qt * 128 + wv * 32;        // head-relative base of wave's rows

  __shared__ __align__(16) char smem[41984];
  char* const lK0 = smem;
  char* const lV0 = smem + 16384;
  char* const lS  = smem + 32768 + wv * 2304;  // 32 rows x 72B

  const char*     kw   = wsK + (size_t)(bh * 32) * 8192;
  const char*     vw   = wsV + (size_t)(bh * 32) * 8192;
  const uint32_t* mrow = wsM + (size_t)(b * 1024 + qrow0 + q31) * 32;
  float*          ag   = attnp + ((size_t)bh * S_ + qrow0) * S_;
  float*          og   = outp  + (size_t)bh * S_ * D_;

  const float invT = 0.08838834764831843f;     // 1/sqrt(128)

  // ---- Q fragments (B-operand of swapped QK): lane holds Q[q31][16ks+8t..+7]
  s16x8 qf[8];
  {
    const float* qrow = q + ((size_t)bh * S_ + qrow0 + q31) * D_ + 8 * t;
    #pragma unroll
    for (int ks = 0; ks < 8; ++ks) {
      f32x4 x0 = *(const f32x4*)(qrow + 16 * ks);
      f32x4 x1 = *(const f32x4*)(qrow + 16 * ks + 4);
      s16x8 h;
      h[0]=f2bf(x0[0]*invT); h[1]=f2bf(x0[1]*invT); h[2]=f2bf(x0[2]*invT); h[3]=f2bf(x0[3]*invT);
      h[4]=f2bf(x1[0]*invT); h[5]=f2bf(x1[1]*invT); h[6]=f2bf(x1[2]*invT); h[7]=f2bf(x1[3]*invT);
      qf[ks] = h;
    }
  }

  // ---- prologue: DMA tile 0 into buffer 0 ----
  #pragma unroll
  for (int rep = 0; rep < 2; ++rep) {
    gl16(kw + rep * 4096 + tid * 16, lK0 + rep * 4096 + wv * 1024);
    gl16(vw + rep * 4096 + tid * 16, lV0 + rep * 4096 + wv * 1024);
  }
  asm volatile("s_waitcnt vmcnt(0) lgkmcnt(0)" ::: "memory");
  __builtin_amdgcn_s_barrier();
  __builtin_amdgcn_sched_barrier(0);

  f32x16 oacc[4];
  #pragma unroll
  for (int dc = 0; dc < 4; ++dc)
    #pragma unroll
    for (int r = 0; r < 16; ++r) oacc[dc][r] = 0.f;

  int cur = 0;
  for (int kt = 0; kt < NKT; ++kt) {
    const bool pf = (kt + 1 < NKT);
    char* lKc = lK0 + cur * 8192;
    char* lVc = lV0 + cur * 8192;

    // ---- (1) mask bitword: one dword per lane (row q31, word kt) ----
    uint32_t mword = mrow[kt];

    // ---- (2) DMA next tile into other buffer (in flight all iteration) ----
    if (pf) {
      const char* kn = kw + (size_t)(kt + 1) * 8192;
      const char* vn = vw + (size_t)(kt + 1) * 8192;
      char* lKn = lK0 + (cur ^ 1) * 8192;
      char* lVn = lV0 + (cur ^ 1) * 8192;
      #pragma unroll
      for (int rep = 0; rep < 2; ++rep) {
        gl16(kn + rep * 4096 + tid * 16, lKn + rep * 4096 + wv * 1024);
        gl16(vn + rep * 4096 + tid * 16, lVn + rep * 4096 + wv * 1024);
      }
    }
    __builtin_amdgcn_sched_barrier(0);   // nothing below moves above the DMA

    // ---- (3) QK^T swapped, 32x32x16: D[kv][q]; lane: q=q31, kv=(r&3)+8(r>>2)+4t
    f32x16 sacc;
    #pragma unroll
    for (int r = 0; r < 16; ++r) sacc[r] = 0.f;
    #pragma unroll
    for (int ks = 0; ks < 8; ++ks) {
      s16x8 kf = *(s16x8*)(lKc + ks * 1024 + lane * 16);
      sacc = __builtin_amdgcn_mfma_f32_32x32x16_bf16(kf, qf[ks], sacc, 0, 0, 0);
    }

    // ---- (4) clip + mask -> lS rows (bf16); kv group 8g+4t+{0..3} per reg quad
    #pragma unroll
    for (int gq = 0; gq < 4; ++gq) {
      s16x4 h4;
      #pragma unroll
      for (int j = 0; j < 4; ++j) {
        float val = fminf(fmaxf(sacc[4 * gq + j], 0.f), 15.f);
        if (!((mword >> (8 * gq + 4 * t + j)) & 1u)) val = 0.f;
        h4[j] = (short)f2bf(val);
      }
      *(s16x4*)(lS + q31 * 72 + 16 * gq + 8 * t) = h4;
    }

    // ---- (5) PV, 32x32x16: A = S rows from lS (lane q=q31, kv=16s+8t..+7) ----
    {
      s16x8 saf0 = *(s16x8*)(lS + q31 * 72 + 16 * t);
      s16x8 saf1 = *(s16x8*)(lS + q31 * 72 + 32 + 16 * t);
      #pragma unroll
      for (int dc = 0; dc < 4; ++dc) {
        s16x8 vb0 = *(s16x8*)(lVc + (dc * 2 + 0) * 1024 + lane * 16);
        oacc[dc] = __builtin_amdgcn_mfma_f32_32x32x16_bf16(saf0, vb0, oacc[dc], 0, 0, 0);
        s16x8 vb1 = *(s16x8*)(lVc + (dc * 2 + 1) * 1024 + lane * 16);
        oacc[dc] = __builtin_amdgcn_mfma_f32_32x32x16_bf16(saf1, vb1, oacc[dc], 0, 0, 0);
      }
    }

    // ---- (6) attn repack: full 128B-per-row segments (8 lanes x 16B) ----
    #pragma unroll
    for (int p = 0; p < 4; ++p) {
      int rr = 8 * p + (lane >> 3);            // 0..31 wave-relative row
      int cb = lane & 7;                       // kv 4cb..+3
      s16x4 sv = *(s16x4*)(lS + rr * 72 + cb * 8);
      f32x4 a;
      a[0]=bf2f((uint16_t)sv[0]); a[1]=bf2f((uint16_t)sv[1]);
      a[2]=bf2f((uint16_t)sv[2]); a[3]=bf2f((uint16_t)sv[3]);
      __builtin_nontemporal_store(a,
          (f32x4*)(ag + (size_t)rr * S_ + kt * BN + cb * 4));
    }

    // ---- (7) barrier: DMA (4 ops) done; 4 attn stores stay in flight ----
    asm volatile("s_waitcnt vmcnt(4) lgkmcnt(0)" ::: "memory");
    __builtin_amdgcn_s_barrier();
    __builtin_amdgcn_sched_barrier(0);
    cur ^= 1;
  }

  // ---- epilogue: O store; 32 consecutive lanes x 4B = 128B segments ----
  #pragma unroll
  for (int dc = 0; dc < 4; ++dc)
    #pragma unroll
    for (int r = 0; r < 16; ++r) {
      int row = qrow0 + (r & 3) + 8 * (r >> 2) + 4 * t;
      __builtin_nontemporal_store(oacc[dc][r], og + (size_t)row * D_ + 32 * dc + q31);
    }
}

// ===================== fallback (r5 kernel, passing) ======================
#define LDS_BARRIER() do {                                   \
    asm volatile("s_waitcnt lgkmcnt(0)" ::: "memory");       \
    __builtin_amdgcn_s_barrier();                            \
    __builtin_amdgcn_sched_barrier(0);                       \
  } while (0)

__global__ __launch_bounds__(NTHREADS)
__attribute__((amdgpu_waves_per_eu(4, 4)))
void attn_relu15_fallback(const float* __restrict__ q, const float* __restrict__ k,
                          const float* __restrict__ v, const int* __restrict__ mask,
                          float* __restrict__ outp, float* __restrict__ attnp)
{
  const int blk = blockIdx.x;
  const int g   = (blk & 7) * 128 + (blk >> 3);
  const int bh  = g >> 4;
  const int qt  = g & 15;
  const int b   = bh >> 4;
  const int tid  = threadIdx.x;
  const int lane = tid & 63;
  const int wq   = tid >> 6;
  const int lhi  = lane >> 4;
  const int llo  = lane & 15;

  __shared__ __align__(16) char smem[36864];
  char* const lK0 = smem;
  char* const lV0 = smem + 16384;
  char* const lS  = smem + 32768 + wq * 1024;

  const float* qg = q + (size_t)bh * (S_ * D_) + (size_t)qt * 64 * D_;
  const float* kg = k + (size_t)bh * (S_ * D_);
  const float* vg = v + (size_t)bh * (S_ * D_);
  const int*   mg = mask  + (size_t)b * S_ * S_ + (size_t)qt * 64 * S_;
  float*       ag = attnp + (size_t)bh * S_ * S_ + (size_t)qt * 64 * S_;
  float*       og = outp  + (size_t)bh * (S_ * D_) + (size_t)qt * 64 * D_;
  const float invT = 0.08838834764831843f;

  #define K_O(rep)   ((tid + NTHREADS * (rep)) * 8)
  #define K_ROW(o)   ((((o) >> 10) & 1) * 16 + (((o) >> 4) & 15))
  #define K_COL(o)   (((o) >> 11) * 32 + (((o) >> 8) & 3) * 8 + (((o) >> 3) & 1) * 4)

  s16x8 qf[4];
  {
    const float* qrow = qg + (size_t)(16 * wq + llo) * D_;
    #pragma unroll
    for (int ks = 0; ks < 4; ++ks) {
      int d0 = 32 * ks + 8 * lhi;
      f32x4 x0 = *(const f32x4*)(qrow + d0);
      f32x4 x1 = *(const f32x4*)(qrow + d0 + 4);
      s16x8 h;
      h[0]=f2bf(x0[0]*invT); h[1]=f2bf(x0[1]*invT); h[2]=f2bf(x0[2]*invT); h[3]=f2bf(x0[3]*invT);
      h[4]=f2bf(x1[0]*invT); h[5]=f2bf(x1[1]*invT); h[6]=f2bf(x1[2]*invT); h[7]=f2bf(x1[3]*invT);
      qf[ks] = h;
    }
  }
  {
    #pragma unroll
    for (int rep = 0; rep < 4; ++rep) {
      int o = K_O(rep);
      f32x4 x = *(const f32x4*)(kg + K_ROW(o) * D_ + K_COL(o));
      s16x4 h; h[0]=f2bf(x[0]); h[1]=f2bf(x[1]); h[2]=f2bf(x[2]); h[3]=f2bf(x[3]);
      *(s16x4*)(lK0 + o) = h;
    }
    #pragma unroll
    for (int rep = 0; rep < 4; ++rep) {
      int bid = (tid >> 2) + 64 * rep;
      int kb = bid >> 5, db = bid & 31, l2 = lane & 3;
      f32x4 x = *(const f32x4*)(vg + (size_t)(kb * 4 + l2) * D_ + db * 4);
      float v0=x[0], v1=x[1], v2=x[2], v3=x[3], t;
      t=(l2&1)?v0:v1; t=__shfl_xor(t,1); if(l2&1)v0=t; else v1=t;
      t=(l2&1)?v2:v3; t=__shfl_xor(t,1); if(l2&1)v2=t; else v3=t;
      t=(l2&2)?v0:v2; t=__shfl_xor(t,2); if(l2&2)v0=t; else v2=t;
      t=(l2&2)?v1:v3; t=__shfl_xor(t,2); if(l2&2)v1=t; else v3=t;
      int dd = db * 4 + l2;
      s16x4 h; h[0]=f2bf(v0); h[1]=f2bf(v1); h[2]=f2bf(v2); h[3]=f2bf(v3);
      *(s16x4*)(lV0 + (dd >> 4) * 1024 + ((kb >> 1) & 3) * 256
                    + (dd & 15) * 16 + (kb & 1) * 8) = h;
    }
  }
  LDS_BARRIER();

  f32x4 oacc[8];
  #pragma unroll
  for (int i = 0; i < 8; ++i) oacc[i] = (f32x4){0.f,0.f,0.f,0.f};

  int cur = 0;
  for (int kt = 0; kt < NKT; ++kt) {
    const bool pf = (kt + 1 < NKT);
    char* lKc = lK0 + cur * 8192;
    char* lVc = lV0 + cur * 8192;
    f32x4 kst[4];
    const float* kgt = kg + (size_t)(kt + 1) * BN * D_;
    if (pf) {
      #pragma unroll
      for (int rep = 0; rep < 4; ++rep) {
        int o = K_O(rep);
        kst[rep] = *(const f32x4*)(kgt + K_ROW(o) * D_ + K_COL(o));
      }
    }
    int mreg[8];
    #pragma unroll
    for (int nt = 0; nt < 2; ++nt)
      #pragma unroll
      for (int j = 0; j < 4; ++j)
        mreg[nt * 4 + j] =
          mg[(size_t)(16 * wq + 4 * lhi + j) * S_ + kt * BN + 16 * nt + llo];

    f32x4 sacc[2];
    sacc[0] = (f32x4){0.f,0.f,0.f,0.f}; sacc[1] = sacc[0];
    #pragma unroll
    for (int ks = 0; ks < 4; ++ks) {
      s16x8 bfr[2];
      #pragma unroll
      for (int nt = 0; nt < 2; ++nt)
        bfr[nt] = *(s16x8*)(lKc + (ks * 2 + nt) * 1024 + lane * 16);
      #pragma unroll
      for (int nt = 0; nt < 2; ++nt)
        sacc[nt] = __builtin_amdgcn_mfma_f32_16x16x32_bf16(qf[ks], bfr[nt], sacc[nt], 0, 0, 0);
    }

    f32x4 vst[4];
    const float* vgt = vg + (size_t)(kt + 1) * BN * D_;
    if (pf) {
      char* lKn = lK0 + (cur ^ 1) * 8192;
      #pragma unroll
      for (int rep = 0; rep < 4; ++rep) {
        f32x4 x = kst[rep];
        s16x4 h; h[0]=f2bf(x[0]); h[1]=f2bf(x[1]); h[2]=f2bf(x[2]); h[3]=f2bf(x[3]);
        *(s16x4*)(lKn + K_O(rep)) = h;
      }
      #pragma unroll
      for (int rep = 0; rep < 4; ++rep) {
        int bid = (tid >> 2) + 64 * rep;
        int kb = bid >> 5, db = bid & 31, l2 = lane & 3;
        vst[rep] = *(const f32x4*)(vgt + (size_t)(kb * 4 + l2) * D_ + db * 4);
      }
    }

    #pragma unroll
    for (int nt = 0; nt < 2; ++nt) {
      char* sb = lS + (2 * nt + (llo >> 3)) * 256 + (llo & 7) * 2;
      #pragma unroll
      for (int j = 0; j < 4; ++j) {
        float val = fminf(fmaxf(sacc[nt][j], 0.f), 15.f);
        if (mreg[nt * 4 + j] == 0) val = 0.f;
        *(uint16_t*)(sb + (4 * lhi + j) * 16) = f2bf(val);
      }
    }
    {
      s16x8 saf = *(s16x8*)(lS + lane * 16);
      #pragma unroll
      for (int nt = 0; nt < 8; ++nt) {
        s16x8 vb = *(s16x8*)(lVc + nt * 1024 + lane * 16);
        oacc[nt] = __builtin_amdgcn_mfma_f32_16x16x32_bf16(saf, vb, oacc[nt], 0, 0, 0);
      }
    }
    #pragma unroll
    for (int p = 0; p < 2; ++p) {
      int r  = 16 * wq + p * 8 + (lane >> 3);
      int cb = lane & 7;
      s16x4 sv = *(s16x4*)(lS + (cb >> 1) * 256 + ((r & 15) * 16) + (cb & 1) * 8);
      f32x4 a;
      a[0]=bf2f((uint16_t)sv[0]); a[1]=bf2f((uint16_t)sv[1]);
      a[2]=bf2f((uint16_t)sv[2]); a[3]=bf2f((uint16_t)sv[3]);
      __builtin_nontemporal_store(a, (f32x4*)(ag + (size_t)r * S_ + kt * BN + cb * 4));
    }
    if (pf) {
      char* lVn = lV0 + (cur ^ 1) * 8192;
      #pragma unroll
      for (int rep = 0; rep < 4; ++rep) {
        int bid = (tid >> 2) + 64 * rep;
        int kb = bid >> 5, db = bid & 31, l2 = lane & 3;
        f32x4 x = vst[rep];
        float v0=x[0], v1=x[1], v2=x[2], v3=x[3], t;
        t=(l2&1)?v0:v1; t=__shfl_xor(t,1); if(l2&1)v0=t; else v1=t;
        t=(l2&1)?v2:v3; t=__shfl_xor(t,1); if(l2&1)v2=t; else v3=t;
        t=(l2&2)?v0:v2; t=__shfl_xor(t,2); if(l2&2)v0=t; else v2=t;
        t=(l2&2)?v1:v3; t=__shfl_xor(t,2); if(l2&2)v1=t; else v3=t;
        int dd = db * 4 + l2;
        s16x4 h; h[0]=f2bf(v0); h[1]=f2bf(v1); h[2]=f2bf(v2); h[3]=f2bf(v3);
        *(s16x4*)(lVn + (dd >> 4) * 1024 + ((kb >> 1) & 3) * 256
                      + (dd & 15) * 16 + (kb & 1) * 8) = h;
      }
    }
    LDS_BARRIER();
    cur ^= 1;
  }
  #pragma unroll
  for (int nt = 0; nt < 8; ++nt) {
    int n = 16 * nt + llo;
    #pragma unroll
    for (int j = 0; j < 4; ++j) {
      int m = 16 * wq + 4 * lhi + j;
      __builtin_nontemporal_store(oacc[nt][j], og + (size_t)m * D_ + n);
    }
  }
}

extern "C" void kernel_launch(void* const* d_in, const int* in_sizes, int n_in,
                              void* d_out, int out_size, void* d_ws, size_t ws_size,
                              hipStream_t stream) {
  const float* q    = (const float*)d_in[0];
  const float* k    = (const float*)d_in[1];
  const float* v    = (const float*)d_in[2];
  const int*   mask = (const int*)d_in[3];
  float* outp  = (float*)d_out;
  float* attnp = outp + (size_t)B_ * H_ * S_ * D_;   // tuple: (out, attn) concat

  if (ws_size >= (size_t)WS_NEED && d_ws != nullptr) {
    char*     wsK = (char*)d_ws;
    char*     wsV = wsK + WSK_BYTES;
    uint32_t* wsM = (uint32_t*)(wsK + WSK_BYTES + WSV_BYTES);
    prepass_kernel<<<8704, 256, 0, stream>>>(k, v, mask, wsK, wsV, wsM);
    attn_relu15_main<<<dim3(512), NTHREADS, 0, stream>>>(
        q, wsK, wsV, wsM, outp, attnp);
  } else {
    attn_relu15_fallback<<<dim3(B_ * H_ * (S_ / 64)), NTHREADS, 0, stream>>>(
        q, k, v, mask, outp, attnp);
  }
}

// Round 14
// 101.110 us; speedup vs baseline: 1.1018x; 1.1018x over previous
//
#include <hip/hip_runtime.h>
#include <stdint.h>

// Shapes (fixed for this problem)
#define B_   4
#define H_   16
#define S_   1024
#define D_   128
#define BM   64                  // Q rows per block
#define BN   32                  // K/V rows per iteration
#define NKT  (S_ / BN)           // 32
#define NTHREADS 256             // 4 waves; each wave owns 16 q-rows

typedef float f32x4 __attribute__((ext_vector_type(4)));
typedef short s16x8 __attribute__((ext_vector_type(8)));   // 8 bf16 (MFMA A/B frag)
typedef short s16x4 __attribute__((ext_vector_type(4)));

static __device__ __forceinline__ uint16_t f2bf(float f) {
  uint32_t u = __float_as_uint(f);
  u += 0x7FFFu + ((u >> 16) & 1u);          // round-to-nearest-even
  return (uint16_t)(u >> 16);
}
static __device__ __forceinline__ float bf2f(uint16_t h) {
  return __uint_as_float((uint32_t)h << 16);
}

// Direct global->LDS DMA, 16B per lane. LDS dst = wave-uniform base + lane*16
// (HW rule); global src is per-lane. Our ws tiles are pre-laid in LDS byte
// order, so src offset == dst offset (both linear).
static __device__ __forceinline__ void gl16(const void* g, void* l) {
  __builtin_amdgcn_global_load_lds(
      (const __attribute__((address_space(1))) unsigned int*)g,
      (__attribute__((address_space(3))) unsigned int*)l, 16, 0, 0);
}

// ws layout: [0,16M) Kbf tiles, [16M,32M) Vbf tiles, [32M,32.5M) mask bitwords.
// K tile (bh,kt): 8192B; chunk16B[(ks*2+nt)*64 + lane] = K[kt*32+16nt+llo][32ks+8lhi..+7]
// V tile (bh,kt): 8192B; chunk16B[nt*64 + lane]        = V[kt*32+8lhi..+7][16nt+llo]
// mask word [b*1024+r][w] = bits of mask[b][r][32w..32w+31]
#define WSK_BYTES  16777216
#define WSV_BYTES  16777216
#define WSM_BYTES  524288
#define WS_NEED    (WSK_BYTES + WSV_BYTES + WSM_BYTES)

// ============================ pre-pass ====================================
__global__ __launch_bounds__(256)
void prepass_kernel(const float* __restrict__ k, const float* __restrict__ v,
                    const int* __restrict__ mask,
                    char* __restrict__ wsK, char* __restrict__ wsV,
                    uint32_t* __restrict__ wsM)
{
  int gid = blockIdx.x * 256 + threadIdx.x;
  if (gid < 1048576) {                       // ---- K chunks ----
    int tile = gid >> 9, c = gid & 511;
    int ks = c >> 7, nt = (c >> 6) & 1, lane = c & 63;
    int row = (tile & 31) * 32 + 16 * nt + (lane & 15);
    int col = 32 * ks + 8 * (lane >> 4);
    const float* src = k + ((size_t)(tile >> 5) * S_ + row) * D_ + col;
    f32x4 x0 = *(const f32x4*)src;
    f32x4 x1 = *(const f32x4*)(src + 4);
    s16x8 h;
    h[0]=f2bf(x0[0]); h[1]=f2bf(x0[1]); h[2]=f2bf(x0[2]); h[3]=f2bf(x0[3]);
    h[4]=f2bf(x1[0]); h[5]=f2bf(x1[1]); h[6]=f2bf(x1[2]); h[7]=f2bf(x1[3]);
    *(s16x8*)(wsK + (size_t)gid * 16) = h;
  } else if (gid < 2097152) {                // ---- V chunks (transposed) ----
    int gv = gid - 1048576;
    int tile = gv >> 9, c = gv & 511;
    int nt = c >> 6, lane = c & 63;
    int d   = 16 * nt + (lane & 15);
    int kv0 = (tile & 31) * 32 + 8 * (lane >> 4);
    const float* src = v + ((size_t)(tile >> 5) * S_ + kv0) * D_ + d;
    s16x8 h;
    #pragma unroll
    for (int i = 0; i < 8; ++i) h[i] = f2bf(src[(size_t)i * D_]);
    *(s16x8*)(wsV + (size_t)gv * 16) = h;
  } else if (gid < 2228224) {                // ---- mask bitwords ----
    int gm = gid - 2097152;                  // = (b*1024 + r)*32 + w
    const int* src = mask + (size_t)(gm >> 5) * S_ + (gm & 31) * 32;
    uint32_t bits = 0;
    #pragma unroll
    for (int i = 0; i < 32; ++i) bits |= (src[i] != 0 ? 1u : 0u) << i;
    wsM[gm] = bits;
  }
}

// ============================ main kernel =================================
// LDS map (36864 B -> 4 blocks/CU, 16 waves/CU):
//  [    0,16384) lK dbuf (8KB each), fragment-major (see ws layout)
//  [16384,32768) lV dbuf (8KB each), fragment-major
//  [32768,36864) lS: per wave 1KB; chunk16B[lane] = S[q=llo][kv=8lhi..+7]
__global__ __launch_bounds__(NTHREADS)
__attribute__((amdgpu_waves_per_eu(4, 4)))
void attn_relu15_main(const float* __restrict__ q,
                      const char* __restrict__ wsK, const char* __restrict__ wsV,
                      const uint32_t* __restrict__ wsM,
                      float* __restrict__ outp, float* __restrict__ attnp)
{
  const int blk = blockIdx.x;
  const int g   = (blk & 7) * 128 + (blk >> 3);   // XCD-grouped bijection
  const int bh  = g >> 4;
  const int qt  = g & 15;
  const int b   = bh >> 4;

  const int tid  = threadIdx.x;
  const int lane = tid & 63;
  const int wq   = tid >> 6;
  const int lhi  = lane >> 4;
  const int llo  = lane & 15;

  __shared__ __align__(16) char smem[36864];
  char* const lK0 = smem;
  char* const lV0 = smem + 16384;
  char* const lS  = smem + 32768 + wq * 1024;

  const float*    qg = q + (size_t)bh * (S_ * D_) + (size_t)qt * BM * D_;
  const char*     kw = wsK + (size_t)(bh * 32) * 8192;
  const char*     vw = wsV + (size_t)(bh * 32) * 8192;
  const uint32_t* mw0 = wsM + ((size_t)b * S_ + qt * BM + 16 * wq) * 32;
  float*          ag = attnp + (size_t)bh * S_ * S_ + (size_t)qt * BM * S_;
  float*          og = outp  + (size_t)bh * (S_ * D_) + (size_t)qt * BM * D_;

  const float invT = 0.08838834764831843f;   // 1/sqrt(128)

  // ---- Q fragments into registers (scaled, bf16), loaded once ----
  s16x8 qf[4];
  {
    const float* qrow = qg + (size_t)(16 * wq + llo) * D_;
    #pragma unroll
    for (int ks = 0; ks < 4; ++ks) {
      int d0 = 32 * ks + 8 * lhi;
      f32x4 x0 = *(const f32x4*)(qrow + d0);
      f32x4 x1 = *(const f32x4*)(qrow + d0 + 4);
      s16x8 h;
      h[0]=f2bf(x0[0]*invT); h[1]=f2bf(x0[1]*invT); h[2]=f2bf(x0[2]*invT); h[3]=f2bf(x0[3]*invT);
      h[4]=f2bf(x1[0]*invT); h[5]=f2bf(x1[1]*invT); h[6]=f2bf(x1[2]*invT); h[7]=f2bf(x1[3]*invT);
      qf[ks] = h;
    }
  }

  // ---- prologue: DMA tile 0 into buffer 0 ----
  #pragma unroll
  for (int rep = 0; rep < 2; ++rep) {
    gl16(kw + rep * 4096 + tid * 16, lK0 + rep * 4096 + wq * 1024);
    gl16(vw + rep * 4096 + tid * 16, lV0 + rep * 4096 + wq * 1024);
  }
  asm volatile("s_waitcnt vmcnt(0) lgkmcnt(0)" ::: "memory");
  __builtin_amdgcn_s_barrier();
  __builtin_amdgcn_sched_barrier(0);

  f32x4 oacc[8];
  #pragma unroll
  for (int i = 0; i < 8; ++i) oacc[i] = (f32x4){0.f,0.f,0.f,0.f};

  int cur = 0;
  for (int kt = 0; kt < NKT; ++kt) {
    const bool pf = (kt + 1 < NKT);
    char* lKc = lK0 + cur * 8192;
    char* lVc = lV0 + cur * 8192;

    // ---- (1) mask bitword loads (oldest vmem ops this iter) ----
    uint32_t mwv[4];
    #pragma unroll
    for (int j = 0; j < 4; ++j)
      mwv[j] = mw0[(size_t)(4 * lhi + j) * 32 + kt];

    // ---- (2) DMA next tile into other buffer (stays in flight all iter) ----
    if (pf) {
      const char* kn = kw + (size_t)(kt + 1) * 8192;
      const char* vn = vw + (size_t)(kt + 1) * 8192;
      char* lKn = lK0 + (cur ^ 1) * 8192;
      char* lVn = lV0 + (cur ^ 1) * 8192;
      #pragma unroll
      for (int rep = 0; rep < 2; ++rep) {
        gl16(kn + rep * 4096 + tid * 16, lKn + rep * 4096 + wq * 1024);
        gl16(vn + rep * 4096 + tid * 16, lVn + rep * 4096 + wq * 1024);
      }
    }
    __builtin_amdgcn_sched_barrier(0);   // pin: nothing below moves above DMA

    // ---- (3) QK^T: 16 q-rows x 32 k-cols per wave ----
    f32x4 sacc[2];
    sacc[0] = (f32x4){0.f,0.f,0.f,0.f}; sacc[1] = sacc[0];
    #pragma unroll
    for (int ks = 0; ks < 4; ++ks) {
      s16x8 bfr[2];
      #pragma unroll
      for (int nt = 0; nt < 2; ++nt)
        bfr[nt] = *(s16x8*)(lKc + (ks * 2 + nt) * 1024 + lane * 16);
      #pragma unroll
      for (int nt = 0; nt < 2; ++nt)
        sacc[nt] = __builtin_amdgcn_mfma_f32_16x16x32_bf16(qf[ks], bfr[nt], sacc[nt], 0, 0, 0);
    }

    // ---- (4) clip + mask -> lS (bf16, fragment-major) ----
    #pragma unroll
    for (int nt = 0; nt < 2; ++nt) {
      char* sb = lS + (2 * nt + (llo >> 3)) * 256 + (llo & 7) * 2;
      #pragma unroll
      for (int j = 0; j < 4; ++j) {
        float val = fminf(fmaxf(sacc[nt][j], 0.f), 15.f);
        if (!((mwv[j] >> (16 * nt + llo)) & 1u)) val = 0.f;
        *(uint16_t*)(sb + (4 * lhi + j) * 16) = f2bf(val);
      }
    }

    // ---- (5) attn repack: lS -> f32, 128B row segments, issued early ----
    #pragma unroll
    for (int p = 0; p < 2; ++p) {
      int r  = 16 * wq + p * 8 + (lane >> 3);
      int cb = lane & 7;
      s16x4 sv = *(s16x4*)(lS + (cb >> 1) * 256 + ((r & 15) * 16) + (cb & 1) * 8);
      f32x4 a;
      a[0]=bf2f((uint16_t)sv[0]); a[1]=bf2f((uint16_t)sv[1]);
      a[2]=bf2f((uint16_t)sv[2]); a[3]=bf2f((uint16_t)sv[3]);
      __builtin_nontemporal_store(a, (f32x4*)(ag + (size_t)r * S_ + kt * BN + cb * 4));
    }

    // ---- (6) PV: O[16 x 128] += S @ V^T (single K=32 step) ----
    {
      s16x8 saf = *(s16x8*)(lS + lane * 16);
      #pragma unroll
      for (int nt = 0; nt < 8; ++nt) {
        s16x8 vb = *(s16x8*)(lVc + nt * 1024 + lane * 16);
        oacc[nt] = __builtin_amdgcn_mfma_f32_16x16x32_bf16(saf, vb, oacc[nt], 0, 0, 0);
      }
    }

    // ---- (7) barrier: wait DMA (4 ops) done, leave 2 attn stores in flight
    asm volatile("s_waitcnt vmcnt(2) lgkmcnt(0)" ::: "memory");
    __builtin_amdgcn_s_barrier();
    __builtin_amdgcn_sched_barrier(0);
    cur ^= 1;
  }

  // ---- epilogue: O store ----
  #pragma unroll
  for (int nt = 0; nt < 8; ++nt) {
    int n = 16 * nt + llo;
    #pragma unroll
    for (int j = 0; j < 4; ++j) {
      int m = 16 * wq + 4 * lhi + j;
      __builtin_nontemporal_store(oacc[nt][j], og + (size_t)m * D_ + n);
    }
  }
}

// ===================== fallback (r5 kernel, passing) ======================
#define LDS_BARRIER() do {                                   \
    asm volatile("s_waitcnt lgkmcnt(0)" ::: "memory");       \
    __builtin_amdgcn_s_barrier();                            \
    __builtin_amdgcn_sched_barrier(0);                       \
  } while (0)

__global__ __launch_bounds__(NTHREADS)
__attribute__((amdgpu_waves_per_eu(4, 4)))
void attn_relu15_fallback(const float* __restrict__ q, const float* __restrict__ k,
                          const float* __restrict__ v, const int* __restrict__ mask,
                          float* __restrict__ outp, float* __restrict__ attnp)
{
  const int blk = blockIdx.x;
  const int g   = (blk & 7) * 128 + (blk >> 3);
  const int bh  = g >> 4;
  const int qt  = g & 15;
  const int b   = bh >> 4;
  const int tid  = threadIdx.x;
  const int lane = tid & 63;
  const int wq   = tid >> 6;
  const int lhi  = lane >> 4;
  const int llo  = lane & 15;

  __shared__ __align__(16) char smem[36864];
  char* const lK0 = smem;
  char* const lV0 = smem + 16384;
  char* const lS  = smem + 32768 + wq * 1024;

  const float* qg = q + (size_t)bh * (S_ * D_) + (size_t)qt * 64 * D_;
  const float* kg = k + (size_t)bh * (S_ * D_);
  const float* vg = v + (size_t)bh * (S_ * D_);
  const int*   mg = mask  + (size_t)b * S_ * S_ + (size_t)qt * 64 * S_;
  float*       ag = attnp + (size_t)bh * S_ * S_ + (size_t)qt * 64 * S_;
  float*       og = outp  + (size_t)bh * (S_ * D_) + (size_t)qt * 64 * D_;
  const float invT = 0.08838834764831843f;

  #define K_O(rep)   ((tid + NTHREADS * (rep)) * 8)
  #define K_ROW(o)   ((((o) >> 10) & 1) * 16 + (((o) >> 4) & 15))
  #define K_COL(o)   (((o) >> 11) * 32 + (((o) >> 8) & 3) * 8 + (((o) >> 3) & 1) * 4)

  s16x8 qf[4];
  {
    const float* qrow = qg + (size_t)(16 * wq + llo) * D_;
    #pragma unroll
    for (int ks = 0; ks < 4; ++ks) {
      int d0 = 32 * ks + 8 * lhi;
      f32x4 x0 = *(const f32x4*)(qrow + d0);
      f32x4 x1 = *(const f32x4*)(qrow + d0 + 4);
      s16x8 h;
      h[0]=f2bf(x0[0]*invT); h[1]=f2bf(x0[1]*invT); h[2]=f2bf(x0[2]*invT); h[3]=f2bf(x0[3]*invT);
      h[4]=f2bf(x1[0]*invT); h[5]=f2bf(x1[1]*invT); h[6]=f2bf(x1[2]*invT); h[7]=f2bf(x1[3]*invT);
      qf[ks] = h;
    }
  }
  {
    #pragma unroll
    for (int rep = 0; rep < 4; ++rep) {
      int o = K_O(rep);
      f32x4 x = *(const f32x4*)(kg + K_ROW(o) * D_ + K_COL(o));
      s16x4 h; h[0]=f2bf(x[0]); h[1]=f2bf(x[1]); h[2]=f2bf(x[2]); h[3]=f2bf(x[3]);
      *(s16x4*)(lK0 + o) = h;
    }
    #pragma unroll
    for (int rep = 0; rep < 4; ++rep) {
      int bid = (tid >> 2) + 64 * rep;
      int kb = bid >> 5, db = bid & 31, l2 = lane & 3;
      f32x4 x = *(const f32x4*)(vg + (size_t)(kb * 4 + l2) * D_ + db * 4);
      float v0=x[0], v1=x[1], v2=x[2], v3=x[3], t;
      t=(l2&1)?v0:v1; t=__shfl_xor(t,1); if(l2&1)v0=t; else v1=t;
      t=(l2&1)?v2:v3; t=__shfl_xor(t,1); if(l2&1)v2=t; else v3=t;
      t=(l2&2)?v0:v2; t=__shfl_xor(t,2); if(l2&2)v0=t; else v2=t;
      t=(l2&2)?v1:v3; t=__shfl_xor(t,2); if(l2&2)v1=t; else v3=t;
      int dd = db * 4 + l2;
      s16x4 h; h[0]=f2bf(v0); h[1]=f2bf(v1); h[2]=f2bf(v2); h[3]=f2bf(v3);
      *(s16x4*)(lV0 + (dd >> 4) * 1024 + ((kb >> 1) & 3) * 256
                    + (dd & 15) * 16 + (kb & 1) * 8) = h;
    }
  }
  LDS_BARRIER();

  f32x4 oacc[8];
  #pragma unroll
  for (int i = 0; i < 8; ++i) oacc[i] = (f32x4){0.f,0.f,0.f,0.f};

  int cur = 0;
  for (int kt = 0; kt < NKT; ++kt) {
    const bool pf = (kt + 1 < NKT);
    char* lKc = lK0 + cur * 8192;
    char* lVc = lV0 + cur * 8192;
    f32x4 kst[4];
    const float* kgt = kg + (size_t)(kt + 1) * BN * D_;
    if (pf) {
      #pragma unroll
      for (int rep = 0; rep < 4; ++rep) {
        int o = K_O(rep);
        kst[rep] = *(const f32x4*)(kgt + K_ROW(o) * D_ + K_COL(o));
      }
    }
    int mreg[8];
    #pragma unroll
    for (int nt = 0; nt < 2; ++nt)
      #pragma unroll
      for (int j = 0; j < 4; ++j)
        mreg[nt * 4 + j] =
          mg[(size_t)(16 * wq + 4 * lhi + j) * S_ + kt * BN + 16 * nt + llo];

    f32x4 sacc[2];
    sacc[0] = (f32x4){0.f,0.f,0.f,0.f}; sacc[1] = sacc[0];
    #pragma unroll
    for (int ks = 0; ks < 4; ++ks) {
      s16x8 bfr[2];
      #pragma unroll
      for (int nt = 0; nt < 2; ++nt)
        bfr[nt] = *(s16x8*)(lKc + (ks * 2 + nt) * 1024 + lane * 16);
      #pragma unroll
      for (int nt = 0; nt < 2; ++nt)
        sacc[nt] = __builtin_amdgcn_mfma_f32_16x16x32_bf16(qf[ks], bfr[nt], sacc[nt], 0, 0, 0);
    }

    f32x4 vst[4];
    const float* vgt = vg + (size_t)(kt + 1) * BN * D_;
    if (pf) {
      char* lKn = lK0 + (cur ^ 1) * 8192;
      #pragma unroll
      for (int rep = 0; rep < 4; ++rep) {
        f32x4 x = kst[rep];
        s16x4 h; h[0]=f2bf(x[0]); h[1]=f2bf(x[1]); h[2]=f2bf(x[2]); h[3]=f2bf(x[3]);
        *(s16x4*)(lKn + K_O(rep)) = h;
      }
      #pragma unroll
      for (int rep = 0; rep < 4; ++rep) {
        int bid = (tid >> 2) + 64 * rep;
        int kb = bid >> 5, db = bid & 31, l2 = lane & 3;
        vst[rep] = *(const f32x4*)(vgt + (size_t)(kb * 4 + l2) * D_ + db * 4);
      }
    }

    #pragma unroll
    for (int nt = 0; nt < 2; ++nt) {
      char* sb = lS + (2 * nt + (llo >> 3)) * 256 + (llo & 7) * 2;
      #pragma unroll
      for (int j = 0; j < 4; ++j) {
        float val = fminf(fmaxf(sacc[nt][j], 0.f), 15.f);
        if (mreg[nt * 4 + j] == 0) val = 0.f;
        *(uint16_t*)(sb + (4 * lhi + j) * 16) = f2bf(val);
      }
    }
    {
      s16x8 saf = *(s16x8*)(lS + lane * 16);
      #pragma unroll
      for (int nt = 0; nt < 8; ++nt) {
        s16x8 vb = *(s16x8*)(lVc + nt * 1024 + lane * 16);
        oacc[nt] = __builtin_amdgcn_mfma_f32_16x16x32_bf16(saf, vb, oacc[nt], 0, 0, 0);
      }
    }
    #pragma unroll
    for (int p = 0; p < 2; ++p) {
      int r  = 16 * wq + p * 8 + (lane >> 3);
      int cb = lane & 7;
      s16x4 sv = *(s16x4*)(lS + (cb >> 1) * 256 + ((r & 15) * 16) + (cb & 1) * 8);
      f32x4 a;
      a[0]=bf2f((uint16_t)sv[0]); a[1]=bf2f((uint16_t)sv[1]);
      a[2]=bf2f((uint16_t)sv[2]); a[3]=bf2f((uint16_t)sv[3]);
      __builtin_nontemporal_store(a, (f32x4*)(ag + (size_t)r * S_ + kt * BN + cb * 4));
    }
    if (pf) {
      char* lVn = lV0 + (cur ^ 1) * 8192;
      #pragma unroll
      for (int rep = 0; rep < 4; ++rep) {
        int bid = (tid >> 2) + 64 * rep;
        int kb = bid >> 5, db = bid & 31, l2 = lane & 3;
        f32x4 x = vst[rep];
        float v0=x[0], v1=x[1], v2=x[2], v3=x[3], t;
        t=(l2&1)?v0:v1; t=__shfl_xor(t,1); if(l2&1)v0=t; else v1=t;
        t=(l2&1)?v2:v3; t=__shfl_xor(t,1); if(l2&1)v2=t; else v3=t;
        t=(l2&2)?v0:v2; t=__shfl_xor(t,2); if(l2&2)v0=t; else v2=t;
        t=(l2&2)?v1:v3; t=__shfl_xor(t,2); if(l2&2)v1=t; else v3=t;
        int dd = db * 4 + l2;
        s16x4 h; h[0]=f2bf(v0); h[1]=f2bf(v1); h[2]=f2bf(v2); h[3]=f2bf(v3);
        *(s16x4*)(lVn + (dd >> 4) * 1024 + ((kb >> 1) & 3) * 256
                      + (dd & 15) * 16 + (kb & 1) * 8) = h;
      }
    }
    LDS_BARRIER();
    cur ^= 1;
  }
  #pragma unroll
  for (int nt = 0; nt < 8; ++nt) {
    int n = 16 * nt + llo;
    #pragma unroll
    for (int j = 0; j < 4; ++j) {
      int m = 16 * wq + 4 * lhi + j;
      __builtin_nontemporal_store(oacc[nt][j], og + (size_t)m * D_ + n);
    }
  }
}

extern "C" void kernel_launch(void* const* d_in, const int* in_sizes, int n_in,
                              void* d_out, int out_size, void* d_ws, size_t ws_size,
                              hipStream_t stream) {
  const float* q    = (const float*)d_in[0];
  const float* k    = (const float*)d_in[1];
  const float* v    = (const float*)d_in[2];
  const int*   mask = (const int*)d_in[3];
  float* outp  = (float*)d_out;
  float* attnp = outp + (size_t)B_ * H_ * S_ * D_;   // tuple: (out, attn) concat

  if (ws_size >= (size_t)WS_NEED && d_ws != nullptr) {
    char*     wsK = (char*)d_ws;
    char*     wsV = wsK + WSK_BYTES;
    uint32_t* wsM = (uint32_t*)(wsK + WSK_BYTES + WSV_BYTES);
    prepass_kernel<<<8704, 256, 0, stream>>>(k, v, mask, wsK, wsV, wsM);
    attn_relu15_main<<<dim3(B_ * H_ * (S_ / BM)), NTHREADS, 0, stream>>>(
        q, wsK, wsV, wsM, outp, attnp);
  } else {
    attn_relu15_fallback<<<dim3(B_ * H_ * (S_ / 64)), NTHREADS, 0, stream>>>(
        q, k, v, mask, outp, attnp);
  }
}